// Round 5
// baseline (631.692 us; speedup 1.0000x reference)
//
#include <hip/hip_runtime.h>

#define NN 100000
#define NE 1600000
#define NLAYERS 5
#define GIN_EPSF 0.5f
#define BN_EPSF 1e-5f
#define NB 391                 // ceil(NN/256) buckets of 256 nodes
#define CAPR 4608              // raw edges capacity per bucket (mean 4096 + 8 sigma)
#define GRID_L 2048
#define NWAVES (GRID_L * 4)

typedef unsigned short bfu;
typedef unsigned short u16x4 __attribute__((ext_vector_type(4)));
typedef float f32x4 __attribute__((ext_vector_type(4)));

__device__ inline float bf2f(bfu u) {
    unsigned x = ((unsigned)u) << 16;
    return __builtin_bit_cast(float, x);
}
__device__ inline bfu f2bf(float f) {
    unsigned x = __builtin_bit_cast(unsigned, f);
    unsigned r = (x + 0x7FFF + ((x >> 16) & 1)) >> 16;
    return (bfu)r;
}
__device__ inline f32x4 cvt4(u16x4 v) {
    f32x4 r;
    r.x = bf2f(v.x); r.y = bf2f(v.y); r.z = bf2f(v.z); r.w = bf2f(v.w);
    return r;
}

// tabs layout (ints): [0]=Kc [1]=TotQ [2+k]=cls_q [66+k]=cls_nodeBase
// [130+k]=cls_quadBase (sentinel at Kc) [200+q]=byq_nodeBase [264+q]=byq_quadBase

// ---------------- embedding gather -> bf16 h0 (+ zero dummy row NN) ----------------
__global__ __launch_bounds__(256) void k_embed(const int* __restrict__ x,
                                               const float* __restrict__ table,
                                               bfu* __restrict__ P) {
    int idx = blockIdx.x * 256 + threadIdx.x;
    if (idx >= (NN + 1) * 16) return;
    int i = idx >> 4, fq = idx & 15;
    u16x4 o = {0, 0, 0, 0};
    if (i < NN) {
        f32x4 v = *(const f32x4*)(table + x[2 * i] * 64 + fq * 4);
        o.x = f2bf(v.x); o.y = f2bf(v.y); o.z = f2bf(v.z); o.w = f2bf(v.w);
    }
    *(u16x4*)(P + (size_t)i * 64 + fq * 4) = o;
}

// ---------------- partition edges into fixed-capacity bucket windows ----------------
__global__ __launch_bounds__(256) void k_part(const int* __restrict__ src,
                                              const int* __restrict__ dst,
                                              int* __restrict__ bcnt,
                                              int* __restrict__ tmp) {
    __shared__ int h[NB];
    __shared__ int hb[NB];
    int t = threadIdx.x;
    for (int k = t; k < NB; k += 256) h[k] = 0;
    __syncthreads();
    int base = blockIdx.x * 2048;
    int v_[8], b_[8], r_[8];
#pragma unroll
    for (int u = 0; u < 8; ++u) {
        int e = base + u * 256 + t;
        if (e < NE) {
            int d = dst[e];
            b_[u] = d >> 8;
            v_[u] = src[e] | ((d & 255) << 20);
            r_[u] = atomicAdd(&h[b_[u]], 1);
        } else {
            b_[u] = -1;
        }
    }
    __syncthreads();
    for (int k = t; k < NB; k += 256)
        hb[k] = h[k] ? (k * CAPR + atomicAdd(&bcnt[k], h[k])) : 0;
    __syncthreads();
#pragma unroll
    for (int u = 0; u < 8; ++u) {
        if (b_[u] >= 0) tmp[hb[b_[u]] + r_[u]] = v_[u];
    }
}

// ---------------- per-bucket: degree count + per-bucket bin histogram ----------------
__global__ __launch_bounds__(256) void k_cnt(const int* __restrict__ tmp,
                                             const int* __restrict__ bcnt,
                                             int* __restrict__ pk,
                                             int* __restrict__ gbh) {
    __shared__ int cnt[256];
    __shared__ int lbh[64];
    int b = blockIdx.x, t = threadIdx.x;
    int n = bcnt[b];
    const int* w = tmp + (size_t)b * CAPR;
    cnt[t] = 0;
    if (t < 64) lbh[t] = 0;
    __syncthreads();
    for (int k = t; k < n; k += 256) atomicAdd(&cnt[w[k] >> 20], 1);
    __syncthreads();
    int node = b * 256 + t;
    int c = cnt[t];
    int pkv = 0;
    if (node < NN) {
        int nq = c ? ((c + 3) >> 2) : 1;     // zero-degree nodes get 1 quad of dummies
        int rl = atomicAdd(&lbh[nq], 1);
        pkv = c | (rl << 9) | (nq << 17);
    }
    pk[b * 256 + t] = pkv;
    __syncthreads();
    if (t < 64) gbh[b * 64 + t] = lbh[t];
}

// ---------------- global scan: per-bin bucket prefixes + class tables ----------------
__global__ void k_scan(const int* __restrict__ gbh, int* __restrict__ gBinBase,
                       int* __restrict__ tabs) {
    __shared__ int tot[64];
    int t = threadIdx.x;   // 64 threads, thread t owns bin t
    int run = 0;
    for (int b = 0; b < NB; ++b) {
        int v = gbh[b * 64 + t];
        gBinBase[b * 64 + t] = run;
        run += v;
    }
    tot[t] = run;
    __syncthreads();
    if (t == 0) {
        int K = 0, nb = 0;
        long qb = 0;
        for (int q = 63; q >= 1; --q) {      // descending degree
            int cN = tot[q];
            if (!cN) continue;
            tabs[2 + K] = q;
            tabs[66 + K] = nb;
            tabs[130 + K] = (int)qb;
            tabs[200 + q] = nb;
            tabs[264 + q] = (int)qb;
            nb += cN;
            qb += (long)cN * q;
            ++K;
        }
        tabs[130 + K] = (int)qb;             // sentinel
        tabs[0] = K;
        tabs[1] = (int)qb;                   // TotQ
    }
}

// ---------------- place: sorted work list + padded srcList ----------------
__global__ __launch_bounds__(256) void k_place(const int* __restrict__ tmp,
                                               const int* __restrict__ bcnt,
                                               const int* __restrict__ pk,
                                               const int* __restrict__ gBinBase,
                                               const int* __restrict__ tabs,
                                               int2* __restrict__ work,
                                               int* __restrict__ srcList) {
    __shared__ int cur[256];
    int b = blockIdx.x, t = threadIdx.x;
    int n = bcnt[b];
    const int* w = tmp + (size_t)b * CAPR;
    int node = b * 256 + t;
    int pkv = pk[b * 256 + t];
    if (node < NN) {
        int c = pkv & 511;
        int rl = (pkv >> 9) & 255;
        int nq = pkv >> 17;
        int rank = gBinBase[b * 64 + nq] + rl;           // rank within class
        int sp = tabs[200 + nq] + rank;                  // global sorted position
        int beg = (tabs[264 + nq] + rank * nq) * 4;
        work[sp] = make_int2(beg, node | (nq << 20));
        cur[t] = beg;
        for (int k = c; k < nq * 4; ++k) srcList[beg + k] = NN;   // dummy zero-row
    }
    __syncthreads();
    for (int k = t; k < n; k += 256) {
        int v = w[k];
        int pos = atomicAdd(&cur[v >> 20], 1);
        srcList[pos] = v & 0xFFFFF;
    }
}

// ---------------- equal-quad wave chunking helper ----------------
__device__ inline int rank_of_quad(long T, int Kc, int TotQ,
                                   const int* s_q, const int* s_nb, const int* s_qb) {
    if (T >= TotQ) return NN;
    int i = 0;
    for (int j = 1; j < Kc; ++j)
        if (T >= s_qb[j]) i = j;
    int q = s_q[i];
    return s_nb[i] + (int)((T - s_qb[i] + q - 1) / q);   // first rank starting at/after T
}

// ---------------- fused layer: equal-work waves, 16-lane groups ----------------
__global__ __launch_bounds__(256) void k_layer(
    const bfu* __restrict__ P, float* __restrict__ Q,
    const int2* __restrict__ work, const int* __restrict__ srcList,
    const int* __restrict__ tabs, float* __restrict__ sums) {
    __shared__ float ssum[64], ssq[64];
    __shared__ int s_q[64], s_nb[64], s_qb[65];
    int t = threadIdx.x;
    if (t < 64) {
        ssum[t] = 0.f; ssq[t] = 0.f;
        s_q[t] = tabs[2 + t];
        s_nb[t] = tabs[66 + t];
    }
    if (t < 65) s_qb[t] = tabs[130 + t];
    __syncthreads();
    int Kc = tabs[0], TotQ = tabs[1];
    int wv = blockIdx.x * 4 + (t >> 6);
    long Ts = (long)wv * TotQ / NWAVES;
    long Te = (long)(wv + 1) * TotQ / NWAVES;
    int n0 = rank_of_quad(Ts, Kc, TotQ, s_q, s_nb, s_qb);
    int n1 = rank_of_quad(Te, Kc, TotQ, s_q, s_nb, s_qb);
    int grp = (t >> 4) & 3;
    int c = t & 15;
    f32x4 lsum = {0.f, 0.f, 0.f, 0.f};
    f32x4 lsq = {0.f, 0.f, 0.f, 0.f};
    for (int sp = n0 + grp; sp < n1; sp += 4) {
        int2 wk = work[sp];
        int beg = wk.x;
        int node = wk.y & 0xFFFFF;
        int nq = wk.y >> 20;
        f32x4 r = cvt4(*(const u16x4*)(P + (size_t)node * 64 + c * 4)) * GIN_EPSF;
        const int4* sl = (const int4*)(srcList + beg);
#pragma unroll 4
        for (int q = 0; q < nq; ++q) {
            int4 s = sl[q];
            f32x4 a = cvt4(*(const u16x4*)(P + (size_t)s.x * 64 + c * 4));
            f32x4 bb = cvt4(*(const u16x4*)(P + (size_t)s.y * 64 + c * 4));
            f32x4 cc = cvt4(*(const u16x4*)(P + (size_t)s.z * 64 + c * 4));
            f32x4 dd = cvt4(*(const u16x4*)(P + (size_t)s.w * 64 + c * 4));
            r += (a + bb) + (cc + dd);
        }
        *(f32x4*)(Q + (size_t)node * 64 + c * 4) = r;
        lsum += r;
        lsq += r * r;
    }
    atomicAdd(&ssum[c * 4 + 0], lsum.x);
    atomicAdd(&ssum[c * 4 + 1], lsum.y);
    atomicAdd(&ssum[c * 4 + 2], lsum.z);
    atomicAdd(&ssum[c * 4 + 3], lsum.w);
    atomicAdd(&ssq[c * 4 + 0], lsq.x);
    atomicAdd(&ssq[c * 4 + 1], lsq.y);
    atomicAdd(&ssq[c * 4 + 2], lsq.z);
    atomicAdd(&ssq[c * 4 + 3], lsq.w);
    __syncthreads();
    if (t < 64) {
        atomicAdd(&sums[t], ssum[t]);
        atomicAdd(&sums[64 + t], ssq[t]);
    }
}

// ---------------- normalize agg -> bf16 h (params from sums inline) ----------------
__global__ __launch_bounds__(256) void k_norm(const float* __restrict__ Q,
                                              const float* __restrict__ sums,
                                              bfu* __restrict__ P) {
    __shared__ float prm[128];
    int t = threadIdx.x;
    if (t < 64) {
        float s = sums[t], sq = sums[64 + t];
        float mean = s / (float)NN;
        float var = fmaxf(sq / (float)NN - mean * mean, 0.f);
        prm[t] = rsqrtf(var + BN_EPSF);
        prm[64 + t] = mean;
    }
    __syncthreads();
    int idx = blockIdx.x * 256 + t;
    if (idx >= (NN + 1) * 16) return;
    int i = idx >> 4, fq = idx & 15;
    u16x4 o = {0, 0, 0, 0};
    if (i < NN) {
        f32x4 v = *(const f32x4*)(Q + (size_t)i * 64 + fq * 4);
        o.x = f2bf((v.x - prm[64 + fq * 4 + 0]) * prm[fq * 4 + 0]);
        o.y = f2bf((v.y - prm[64 + fq * 4 + 1]) * prm[fq * 4 + 1]);
        o.z = f2bf((v.z - prm[64 + fq * 4 + 2]) * prm[fq * 4 + 2]);
        o.w = f2bf((v.w - prm[64 + fq * 4 + 3]) * prm[fq * 4 + 3]);
    }
    *(u16x4*)(P + (size_t)i * 64 + fq * 4) = o;
}

// ---------------- final normalize -> fp32 out ----------------
__global__ __launch_bounds__(256) void k_final(const float* __restrict__ Q,
                                               const float* __restrict__ sums,
                                               float* __restrict__ out) {
    __shared__ float prm[128];
    int t = threadIdx.x;
    if (t < 64) {
        float s = sums[t], sq = sums[64 + t];
        float mean = s / (float)NN;
        float var = fmaxf(sq / (float)NN - mean * mean, 0.f);
        prm[t] = rsqrtf(var + BN_EPSF);
        prm[64 + t] = mean;
    }
    __syncthreads();
    int idx = blockIdx.x * 256 + t;
    if (idx >= NN * 16) return;
    int i = idx >> 4, fq = idx & 15;
    f32x4 v = *(const f32x4*)(Q + (size_t)i * 64 + fq * 4);
    f32x4 o;
    o.x = (v.x - prm[64 + fq * 4 + 0]) * prm[fq * 4 + 0];
    o.y = (v.y - prm[64 + fq * 4 + 1]) * prm[fq * 4 + 1];
    o.z = (v.z - prm[64 + fq * 4 + 2]) * prm[fq * 4 + 2];
    o.w = (v.w - prm[64 + fq * 4 + 3]) * prm[fq * 4 + 3];
    *(f32x4*)(out + (size_t)i * 64 + fq * 4) = o;
}

extern "C" void kernel_launch(void* const* d_in, const int* in_sizes, int n_in,
                              void* d_out, int out_size, void* d_ws, size_t ws_size,
                              hipStream_t stream) {
    const int* x = (const int*)d_in[0];          // (NN,2)
    const int* ei = (const int*)d_in[1];         // (2,NE)
    const float* table = (const float*)d_in[2];  // (120,64)
    const int* src = ei;
    const int* dst = ei + NE;
    float* out = (float*)d_out;

    // workspace carve-up (~55 MB)
    bfu* P = (bfu*)d_ws;                                   // (NN+1)*64 bf16
    float* Q = (float*)(P + (size_t)(NN + 1) * 64);        // NN*64 f32
    int* srcList = (int*)(Q + (size_t)NN * 64);            // NE + 4*NN
    int* tmp = srcList + (NE + 4 * NN);                    // NB*CAPR
    int2* work = (int2*)(tmp + (size_t)NB * CAPR);         // NN int2
    int* pk = (int*)(work + NN);                           // NB*256
    int* gBinBase = pk + NB * 256;                         // NB*64
    int* gbh = gBinBase + NB * 64;                         // NB*64
    int* bcnt = gbh + NB * 64;                             // NB
    float* sums = (float*)(bcnt + NB);                     // 5*128
    int* tabs = (int*)(sums + NLAYERS * 128);              // 512

    // zero bcnt + all sums slices in one memset
    hipMemsetAsync(bcnt, 0, (NB + NLAYERS * 128) * sizeof(int), stream);

    k_embed<<<((NN + 1) * 16 + 255) / 256, 256, 0, stream>>>(x, table, P);

    // CSR build: bucket partition -> global degree sort -> padded placement
    const int NPB = (NE + 2047) / 2048;  // 782
    k_part<<<NPB, 256, 0, stream>>>(src, dst, bcnt, tmp);
    k_cnt<<<NB, 256, 0, stream>>>(tmp, bcnt, pk, gbh);
    k_scan<<<1, 64, 0, stream>>>(gbh, gBinBase, tabs);
    k_place<<<NB, 256, 0, stream>>>(tmp, bcnt, pk, gBinBase, tabs, work, srcList);

    // 5 layers
    for (int L = 0; L < NLAYERS; ++L) {
        float* sL = sums + L * 128;
        k_layer<<<GRID_L, 256, 0, stream>>>(P, Q, work, srcList, tabs, sL);
        if (L < NLAYERS - 1)
            k_norm<<<((NN + 1) * 16 + 255) / 256, 256, 0, stream>>>(Q, sL, P);
        else
            k_final<<<(NN * 16 + 255) / 256, 256, 0, stream>>>(Q, sL, out);
    }
}